// Round 10
// baseline (463.462 us; speedup 1.0000x reference)
//
#include <hip/hip_runtime.h>
#include <stdint.h>

#define EPS_BN 1e-5f

typedef __attribute__((ext_vector_type(8))) short short8v;   // 8 bf16 = 4 VGPR
typedef __attribute__((ext_vector_type(4))) float f32x4;     // MFMA accumulator

__device__ __forceinline__ unsigned rne_bf16(float f) {      // round-to-nearest-even
    unsigned u = __float_as_uint(f);
    return (u + 0x7FFFu + ((u >> 16) & 1u)) >> 16;
}

// ============================================================================
// merged prep: [0,cvB) x->bf16 | [cvB,cvB+256) wt0/wt1 | rest: head=-1, deg=0
// ============================================================================
extern "C" __global__ __launch_bounds__(256)
void prep_kernel(const float4* __restrict__ x, uint2* __restrict__ x16, long n4, int cvB,
                 const float* __restrict__ Wl0, const float* __restrict__ Wr0,
                 unsigned short* __restrict__ Wt0,
                 const float* __restrict__ Wl1, const float* __restrict__ Wr1,
                 unsigned short* __restrict__ Wt1,
                 int* __restrict__ head, int* __restrict__ deg, int Nn) {
    int b = blockIdx.x;
    if (b < cvB) {
        long i = (long)b * 256 + threadIdx.x;
        long stride = (long)cvB * 256;
        for (; i < n4; i += stride) {
            float4 v = x[i];
            uint2 o;
            o.x = rne_bf16(v.x) | (rne_bf16(v.y) << 16);
            o.y = rne_bf16(v.z) | (rne_bf16(v.w) << 16);
            x16[i] = o;
        }
    } else if (b < cvB + 256) {
        int wb = b - cvB;
        const float* Wl = (wb < 128) ? Wl0 : Wl1;
        const float* Wr = (wb < 128) ? Wr0 : Wr1;
        unsigned short* Wt = (wb < 128) ? Wt0 : Wt1;
        int idx = (wb & 127) * 256 + threadIdx.x;
        int col = idx >> 8, k = idx & 255;
        float v = (k < 128) ? Wl[(size_t)k * 128 + col]
                            : Wr[(size_t)(k - 128) * 128 + col];
        Wt[(size_t)col * 256 + k] = (unsigned short)rne_bf16(v);
    } else {
        int i = (b - cvB - 256) * 256 + threadIdx.x;
        if (i < Nn) { head[i] = -1; deg[i] = 0; }
    }
}

// ============================================================================
// linked-list + degree histogram in one ei pass
// ============================================================================
extern "C" __global__ __launch_bounds__(256)
void link_hist_kernel(const int* __restrict__ ei, int* __restrict__ head,
                      uint2* __restrict__ pair, int* __restrict__ deg, int E) {
    int e = blockIdx.x * 256 + threadIdx.x;
    if (e < E) {
        int src = ei[e];
        int dst = ei[E + e];
        int old = atomicExch(&head[dst], e);
        uint2 p; p.x = (unsigned)src; p.y = (unsigned)old;
        pair[e] = p;                 // coalesced 8B write
        atomicAdd(&deg[dst], 1);     // L2-resident 400KB
    }
}

// ---- device-wide exclusive scan (3 kernels, 1024 elems/block) --------------
extern "C" __global__ __launch_bounds__(256)
void block_sum_kernel(const int* __restrict__ deg, int* __restrict__ bsum, int Nn) {
    __shared__ int tsum[256];
    int t = threadIdx.x;
    int base = blockIdx.x * 1024 + t * 4;
    int s = 0;
#pragma unroll
    for (int j = 0; j < 4; ++j) {
        int i = base + j;
        if (i < Nn) s += deg[i];
    }
    tsum[t] = s;
    __syncthreads();
    for (int off = 128; off > 0; off >>= 1) {
        if (t < off) tsum[t] += tsum[t + off];
        __syncthreads();
    }
    if (t == 0) bsum[blockIdx.x] = tsum[0];
}

extern "C" __global__ __launch_bounds__(1024)
void scan_bsums_kernel(const int* __restrict__ bsum, int* __restrict__ boff, int NB) {
    __shared__ int sh[1024];
    int t = threadIdx.x;
    int v = (t < NB) ? bsum[t] : 0;
    sh[t] = v;
    __syncthreads();
    for (int off = 1; off < 1024; off <<= 1) {
        int add = (t >= off) ? sh[t - off] : 0;
        __syncthreads();
        sh[t] += add;
        __syncthreads();
    }
    if (t < NB) boff[t] = sh[t] - v;   // exclusive
}

extern "C" __global__ __launch_bounds__(256)
void scan_apply_kernel(const int* __restrict__ deg, const int* __restrict__ boff,
                       int* __restrict__ row_start, int Nn) {
    __shared__ int tsum[256];
    int t = threadIdx.x;
    int base = blockIdx.x * 1024 + t * 4;
    int v[4];
    int s = 0;
#pragma unroll
    for (int j = 0; j < 4; ++j) {
        int i = base + j;
        v[j] = (i < Nn) ? deg[i] : 0;
        s += v[j];
    }
    tsum[t] = s;
    __syncthreads();
    for (int off = 1; off < 256; off <<= 1) {
        int add = (t >= off) ? tsum[t - off] : 0;
        __syncthreads();
        tsum[t] += add;
        __syncthreads();
    }
    int run = boff[blockIdx.x] + (t ? tsum[t - 1] : 0);
#pragma unroll
    for (int j = 0; j < 4; ++j) {
        int i = base + j;
        if (i < Nn) {
            row_start[i] = run;
            run += v[j];
        }
    }
    if (blockIdx.x == gridDim.x - 1 && t == 255)
        row_start[Nn] = boff[blockIdx.x] + tsum[255];
}

// ============================================================================
// gather-max (layer 1) + CSR emit: 16 lanes/node, uint4 per lane.
// Walks the chain (paying the chase once), lane 0 flattens src ids into
// ssrc[row_start[node]..] for reuse by the layer-2 CSR gather.
// Also zeroes stats0[0..255] from block 0.
// ============================================================================
extern "C" __global__ __launch_bounds__(256, 8)
void gather_max_ll16_kernel(const uint4* __restrict__ x16r, const int* __restrict__ head,
                            const uint2* __restrict__ pair,
                            const int* __restrict__ row_start, int* __restrict__ ssrc,
                            uint4* __restrict__ agg16, float* __restrict__ stats, int Nn) {
    if (blockIdx.x == 0 && threadIdx.x < 256) stats[threadIdx.x] = 0.0f;
    int t = blockIdx.x * 256 + threadIdx.x;
    int node = t >> 4;
    if (node >= Nn) return;
    int lane = t & 15;
    int e = head[node];
    uint4 out;
    if (e >= 0) {
        int wp = row_start[node];
        uint2 p = pair[e];
        if (lane == 0) ssrc[wp] = (int)p.x;
        ++wp;
        uint4 r = x16r[(size_t)p.x * 16 + lane];
        float a0 = __uint_as_float(r.x << 16), a1 = __uint_as_float(r.x);
        float a2 = __uint_as_float(r.y << 16), a3 = __uint_as_float(r.y);
        float a4 = __uint_as_float(r.z << 16), a5 = __uint_as_float(r.z);
        float a6 = __uint_as_float(r.w << 16), a7 = __uint_as_float(r.w);
        int en = (int)p.y;
        while (en >= 0) {
            uint2 pn = pair[en];                       // single dependent 8B load
            if (lane == 0) ssrc[wp] = (int)pn.x;
            ++wp;
            uint4 v = x16r[(size_t)pn.x * 16 + lane];  // row load, overlaps chase
            en = (int)pn.y;
            a0 = fmaxf(a0, __uint_as_float(v.x << 16));
            a1 = fmaxf(a1, __uint_as_float(v.x));
            a2 = fmaxf(a2, __uint_as_float(v.y << 16));
            a3 = fmaxf(a3, __uint_as_float(v.y));
            a4 = fmaxf(a4, __uint_as_float(v.z << 16));
            a5 = fmaxf(a5, __uint_as_float(v.z));
            a6 = fmaxf(a6, __uint_as_float(v.w << 16));
            a7 = fmaxf(a7, __uint_as_float(v.w));
        }
        out.x = (__float_as_uint(a0) >> 16) | (__float_as_uint(a1) & 0xFFFF0000u);
        out.y = (__float_as_uint(a2) >> 16) | (__float_as_uint(a3) & 0xFFFF0000u);
        out.z = (__float_as_uint(a4) >> 16) | (__float_as_uint(a5) & 0xFFFF0000u);
        out.w = (__float_as_uint(a6) >> 16) | (__float_as_uint(a7) & 0xFFFF0000u);
    } else {
        out.x = out.y = out.z = out.w = 0u;   // PyG fills empty segments with 0
    }
    agg16[(size_t)node * 16 + lane] = out;
}

// ============================================================================
// CSR gather-max + fused BN0 (layer 2):
//   agg2 = relu(bn0(max over neighbors of h1))   [monotone since gamma0 > 0]
//   y1   = relu(bn0(h1[node]))                   [lin_r input for gemm2]
// edge list read CONTIGUOUSLY from ssrc (1 sector / 16 edges). 2-way unroll.
// scale/shift staged transposed in LDS (stride-1, conflict-free).
// Also zeroes stats1[0..255] from block 0.
// ============================================================================
#define FM8A(v)                                             \
    a0 = fmaxf(a0, __uint_as_float((v).x << 16));           \
    a1 = fmaxf(a1, __uint_as_float((v).x));                 \
    a2 = fmaxf(a2, __uint_as_float((v).y << 16));           \
    a3 = fmaxf(a3, __uint_as_float((v).y));                 \
    a4 = fmaxf(a4, __uint_as_float((v).z << 16));           \
    a5 = fmaxf(a5, __uint_as_float((v).z));                 \
    a6 = fmaxf(a6, __uint_as_float((v).w << 16));           \
    a7 = fmaxf(a7, __uint_as_float((v).w));

extern "C" __global__ __launch_bounds__(256, 8)
void gather_max_bn_csr_kernel(const uint4* __restrict__ h1r,
                              const int* __restrict__ row_start,
                              const int* __restrict__ ssrc,
                              const float* __restrict__ stats0,
                              const float* __restrict__ gamma,
                              const float* __restrict__ beta, float inv_n,
                              uint4* __restrict__ agg16, uint4* __restrict__ y16,
                              float* __restrict__ stats1, int Nn) {
    __shared__ float scT[8][17];   // [j][lane] : c = lane*8+j
    __shared__ float shT[8][17];
    {
        int t = threadIdx.x;
        if (t < 128) {
            float mu = stats0[t] * inv_n;
            float var = stats0[128 + t] * inv_n - mu * mu;
            float sc = gamma[t] * rsqrtf(var + EPS_BN);
            scT[t & 7][t >> 3] = sc;
            shT[t & 7][t >> 3] = beta[t] - mu * sc;
        }
        __syncthreads();
    }
    if (blockIdx.x == 0 && threadIdx.x < 256) stats1[threadIdx.x] = 0.0f;

    int t = blockIdx.x * 256 + threadIdx.x;
    int node = t >> 4;
    if (node >= Nn) return;
    int lane = t & 15;

    float sc[8], sh[8];
#pragma unroll
    for (int j = 0; j < 8; ++j) {
        sc[j] = scT[j][lane];      // stride-1 across the 16-lane group
        sh[j] = shT[j][lane];
    }

    // ---- own row -> y1 = relu(bn(h1[node])) ----
    {
        uint4 r = h1r[(size_t)node * 16 + lane];
        float v0 = __uint_as_float(r.x << 16), v1 = __uint_as_float(r.x & 0xFFFF0000u);
        float v2 = __uint_as_float(r.y << 16), v3 = __uint_as_float(r.y & 0xFFFF0000u);
        float v4 = __uint_as_float(r.z << 16), v5 = __uint_as_float(r.z & 0xFFFF0000u);
        float v6 = __uint_as_float(r.w << 16), v7 = __uint_as_float(r.w & 0xFFFF0000u);
        v0 = fmaxf(fmaf(v0, sc[0], sh[0]), 0.f);
        v1 = fmaxf(fmaf(v1, sc[1], sh[1]), 0.f);
        v2 = fmaxf(fmaf(v2, sc[2], sh[2]), 0.f);
        v3 = fmaxf(fmaf(v3, sc[3], sh[3]), 0.f);
        v4 = fmaxf(fmaf(v4, sc[4], sh[4]), 0.f);
        v5 = fmaxf(fmaf(v5, sc[5], sh[5]), 0.f);
        v6 = fmaxf(fmaf(v6, sc[6], sh[6]), 0.f);
        v7 = fmaxf(fmaf(v7, sc[7], sh[7]), 0.f);
        uint4 o;
        o.x = rne_bf16(v0) | (rne_bf16(v1) << 16);
        o.y = rne_bf16(v2) | (rne_bf16(v3) << 16);
        o.z = rne_bf16(v4) | (rne_bf16(v5) << 16);
        o.w = rne_bf16(v6) | (rne_bf16(v7) << 16);
        y16[(size_t)node * 16 + lane] = o;
    }

    // ---- neighbor max over contiguous CSR edge list ----
    int beg = row_start[node];
    int end = row_start[node + 1];
    uint4 out;
    if (beg < end) {
        int s0 = ssrc[beg];
        uint4 r = h1r[(size_t)s0 * 16 + lane];
        float a0 = __uint_as_float(r.x << 16), a1 = __uint_as_float(r.x);
        float a2 = __uint_as_float(r.y << 16), a3 = __uint_as_float(r.y);
        float a4 = __uint_as_float(r.z << 16), a5 = __uint_as_float(r.z);
        float a6 = __uint_as_float(r.w << 16), a7 = __uint_as_float(r.w);
        int i = beg + 1;
        if (((end - beg) & 1) == 0 && i < end) {   // make remainder even
            int s = ssrc[i];
            uint4 v = h1r[(size_t)s * 16 + lane];
            FM8A(v);
            ++i;
        }
        for (; i < end; i += 2) {
            int sa = ssrc[i];
            int sb = ssrc[i + 1];
            uint4 va = h1r[(size_t)sa * 16 + lane];
            uint4 vb = h1r[(size_t)sb * 16 + lane];
            FM8A(va);
            FM8A(vb);
        }
        // clean hi-garbage before the affine map
        a1 = __uint_as_float(__float_as_uint(a1) & 0xFFFF0000u);
        a3 = __uint_as_float(__float_as_uint(a3) & 0xFFFF0000u);
        a5 = __uint_as_float(__float_as_uint(a5) & 0xFFFF0000u);
        a7 = __uint_as_float(__float_as_uint(a7) & 0xFFFF0000u);
        a0 = fmaxf(fmaf(a0, sc[0], sh[0]), 0.f);
        a1 = fmaxf(fmaf(a1, sc[1], sh[1]), 0.f);
        a2 = fmaxf(fmaf(a2, sc[2], sh[2]), 0.f);
        a3 = fmaxf(fmaf(a3, sc[3], sh[3]), 0.f);
        a4 = fmaxf(fmaf(a4, sc[4], sh[4]), 0.f);
        a5 = fmaxf(fmaf(a5, sc[5], sh[5]), 0.f);
        a6 = fmaxf(fmaf(a6, sc[6], sh[6]), 0.f);
        a7 = fmaxf(fmaf(a7, sc[7], sh[7]), 0.f);
        out.x = rne_bf16(a0) | (rne_bf16(a1) << 16);
        out.y = rne_bf16(a2) | (rne_bf16(a3) << 16);
        out.z = rne_bf16(a4) | (rne_bf16(a5) << 16);
        out.w = rne_bf16(a6) | (rne_bf16(a7) << 16);
    } else {
        out.x = out.y = out.z = out.w = 0u;   // PyG 0-fill (pre-GEMM, no BN)
    }
    agg16[(size_t)node * 16 + lane] = out;
}

// ============================================================================
// MFMA GEMM: acc = [agg16 | xin16] @ Wt^T + bias, fused BN col-stats.
// OUT_BF16=1 -> write h as bf16 (2B stores); else fp32.
// ============================================================================
template <int OUT_BF16>
__device__ __forceinline__
void gemm_bf16_body(const unsigned short* __restrict__ agg16,
                    const unsigned short* __restrict__ xin16,
                    const unsigned short* __restrict__ Wt,
                    const float* __restrict__ bias,
                    void* __restrict__ hout, float* __restrict__ stats, int nrows) {
    __shared__ float redS[4][128];
    __shared__ float redQ[4][128];

    const int t = threadIdx.x;
    const int w = t >> 6, l = t & 63;
    const int wm = w >> 1, wn = w & 1;
    const int r16 = l & 15, g = l >> 4;
    const int blockRow = blockIdx.x * 128;
    const int colBase = wn * 64;

    f32x4 acc[4][4];
#pragma unroll
    for (int m = 0; m < 4; ++m)
#pragma unroll
        for (int n = 0; n < 4; ++n) acc[m][n] = (f32x4){0.f, 0.f, 0.f, 0.f};

    const short8v az = {0, 0, 0, 0, 0, 0, 0, 0};

#pragma unroll
    for (int kt = 0; kt < 8; ++kt) {
        const unsigned short* Asrc = (kt < 4) ? agg16 : xin16;
        const int kofs = (kt < 4) ? kt * 32 : kt * 32 - 128;

        short8v b[4];
#pragma unroll
        for (int n = 0; n < 4; ++n) {
            int col = colBase + n * 16 + r16;
            b[n] = *(const short8v*)(Wt + (size_t)col * 256 + kt * 32 + g * 8);
        }
        short8v a[4];
#pragma unroll
        for (int m = 0; m < 4; ++m) {
            int row = blockRow + wm * 64 + m * 16 + r16;
            a[m] = (row < nrows)
                 ? *(const short8v*)(Asrc + (size_t)row * 128 + kofs + g * 8)
                 : az;
        }
#pragma unroll
        for (int m = 0; m < 4; ++m)
#pragma unroll
            for (int n = 0; n < 4; ++n)
                acc[m][n] = __builtin_amdgcn_mfma_f32_16x16x32_bf16(a[m], b[n], acc[m][n], 0, 0, 0);
    }

    // ---- epilogue: bias, store h, fused BN stats ----
    for (int i = t; i < 512; i += 256) {
        ((float*)redS)[i] = 0.f;
        ((float*)redQ)[i] = 0.f;
    }
    __syncthreads();

    float bcol[4];
#pragma unroll
    for (int n = 0; n < 4; ++n) bcol[n] = bias[colBase + n * 16 + r16];

    float s4[4] = {0.f, 0.f, 0.f, 0.f};
    float q4[4] = {0.f, 0.f, 0.f, 0.f};
#pragma unroll
    for (int m = 0; m < 4; ++m) {
#pragma unroll
        for (int reg = 0; reg < 4; ++reg) {
            int row = blockRow + wm * 64 + m * 16 + g * 4 + reg;   // C/D: row=(l>>4)*4+reg
            if (row < nrows) {
#pragma unroll
                for (int n = 0; n < 4; ++n) {
                    float o = acc[m][n][reg] + bcol[n];
                    int col = colBase + n * 16 + r16;               // col=l&15
                    if (OUT_BF16)
                        ((unsigned short*)hout)[(size_t)row * 128 + col] =
                            (unsigned short)rne_bf16(o);
                    else
                        ((float*)hout)[(size_t)row * 128 + col] = o;
                    s4[n] += o;
                    q4[n] += o * o;
                }
            }
        }
    }
#pragma unroll
    for (int n = 0; n < 4; ++n) {     // reduce over the 4 k-groups (same col)
        s4[n] += __shfl_xor(s4[n], 16, 64);
        s4[n] += __shfl_xor(s4[n], 32, 64);
        q4[n] += __shfl_xor(q4[n], 16, 64);
        q4[n] += __shfl_xor(q4[n], 32, 64);
    }
    if (g == 0) {
#pragma unroll
        for (int n = 0; n < 4; ++n) {
            redS[w][colBase + n * 16 + r16] = s4[n];
            redQ[w][colBase + n * 16 + r16] = q4[n];
        }
    }
    __syncthreads();
    if (t < 128) {
        float s = redS[0][t] + redS[1][t] + redS[2][t] + redS[3][t];
        float q = redQ[0][t] + redQ[1][t] + redQ[2][t] + redQ[3][t];
        atomicAdd(&stats[t], s);
        atomicAdd(&stats[128 + t], q);
    }
}

extern "C" __global__ __launch_bounds__(256)
void gemm_bf16_out16_kernel(const unsigned short* __restrict__ agg16,
                            const unsigned short* __restrict__ xin16,
                            const unsigned short* __restrict__ Wt,
                            const float* __restrict__ bias,
                            unsigned short* __restrict__ h, float* __restrict__ stats,
                            int nrows) {
    gemm_bf16_body<1>(agg16, xin16, Wt, bias, h, stats, nrows);
}

extern "C" __global__ __launch_bounds__(256)
void gemm_bf16_out32_kernel(const unsigned short* __restrict__ agg16,
                            const unsigned short* __restrict__ xin16,
                            const unsigned short* __restrict__ Wt,
                            const float* __restrict__ bias,
                            float* __restrict__ h, float* __restrict__ stats,
                            int nrows) {
    gemm_bf16_body<0>(agg16, xin16, Wt, bias, h, stats, nrows);
}

// ============================================================================
// final BN+ReLU in place fp32 (finalize fused per block)
// ============================================================================
extern "C" __global__ __launch_bounds__(256)
void bn_relu_f32_kernel(float4* __restrict__ h, const float* __restrict__ stats,
                        const float* __restrict__ gamma, const float* __restrict__ beta,
                        float inv_n, long n4) {
    __shared__ float s_ss[256];
    {
        int t = threadIdx.x;
        if (t < 128) {
            float mu = stats[t] * inv_n;
            float var = stats[128 + t] * inv_n - mu * mu;
            float sc = gamma[t] * rsqrtf(var + EPS_BN);
            s_ss[t] = sc;
            s_ss[128 + t] = beta[t] - mu * sc;
        }
        __syncthreads();
    }
    long i = (long)blockIdx.x * blockDim.x + threadIdx.x;
    long stride = (long)gridDim.x * blockDim.x;
    for (; i < n4; i += stride) {
        int c4 = (int)(i & 31) * 4;
        float4 v = h[i];
        v.x = fmaxf(fmaf(v.x, s_ss[c4 + 0], s_ss[128 + c4 + 0]), 0.f);
        v.y = fmaxf(fmaf(v.y, s_ss[c4 + 1], s_ss[128 + c4 + 1]), 0.f);
        v.z = fmaxf(fmaf(v.z, s_ss[c4 + 2], s_ss[128 + c4 + 2]), 0.f);
        v.w = fmaxf(fmaf(v.w, s_ss[c4 + 3], s_ss[128 + c4 + 3]), 0.f);
        h[i] = v;
    }
}

// ============================================================================
// fallback path (fp32 atomic scatter-max + VALU GEMM) — only if ws too small
// ============================================================================
__device__ __forceinline__ unsigned map_f(float f) {
    unsigned u = __float_as_uint(f);
    return (u & 0x80000000u) ? ~u : (u | 0x80000000u);
}
__device__ __forceinline__ float unmap_f(unsigned m) {
    return (m & 0x80000000u) ? __uint_as_float(m & 0x7FFFFFFFu) : __uint_as_float(~m);
}

extern "C" __global__ __launch_bounds__(256)
void init_sentinel_kernel(uint4* __restrict__ agg, long n4) {
    uint4 z = {0u, 0u, 0u, 0u};
    long i = (long)blockIdx.x * blockDim.x + threadIdx.x;
    long stride = (long)gridDim.x * blockDim.x;
    for (; i < n4; i += stride) agg[i] = z;
}

extern "C" __global__ __launch_bounds__(256)
void scatter_max_kernel(const float4* __restrict__ xin, const int* __restrict__ ei,
                        unsigned* __restrict__ agg, int E) {
    int t = blockIdx.x * 256 + threadIdx.x;
    int e = t >> 5;
    if (e >= E) return;
    int f4 = t & 31;
    int src = ei[e];
    int dst = ei[E + e];
    float4 v = xin[(size_t)src * 32 + f4];
    unsigned* p = agg + (size_t)dst * 128 + (size_t)f4 * 4;
    atomicMax(p + 0, map_f(v.x));
    atomicMax(p + 1, map_f(v.y));
    atomicMax(p + 2, map_f(v.z));
    atomicMax(p + 3, map_f(v.w));
}

extern "C" __global__ __launch_bounds__(256)
void unmap_kernel(unsigned* __restrict__ agg, long n) {
    long i = (long)blockIdx.x * blockDim.x + threadIdx.x;
    long stride = (long)gridDim.x * blockDim.x;
    for (; i < n; i += stride) {
        unsigned u = agg[i];
        agg[i] = __float_as_uint(u ? unmap_f(u) : 0.0f);
    }
}

extern "C" __global__
void zero_stats_kernel(float* __restrict__ stats) {
    stats[threadIdx.x] = 0.0f;
}

extern "C" __global__ __launch_bounds__(256)
void gemm_kernel(const float* __restrict__ agg, const float* __restrict__ xin,
                 const float* __restrict__ Wl, const float* __restrict__ Wr,
                 const float* __restrict__ bias, float* __restrict__ h,
                 float* __restrict__ stats, int nrows) {
    __shared__ __align__(16) float As[64][36];
    __shared__ __align__(16) float Bs[32][136];
    __shared__ float redS[4][128];
    __shared__ float redQ[4][128];

    const int t = threadIdx.x;
    const int tx = t & 15;
    const int ty = t >> 4;
    const int tx8 = tx * 8;
    const int ty4 = ty * 4;
    const int blockRow = blockIdx.x * 64;

    float acc[4][8];
#pragma unroll
    for (int j = 0; j < 4; ++j)
#pragma unroll
        for (int c = 0; c < 8; ++c) acc[j][c] = 0.0f;

    for (int kt = 0; kt < 8; ++kt) {
        const int k0 = kt * 32;
        const bool isAgg = (kt < 4);
        const float* W = isAgg ? Wl : Wr;
        const float* Asrc = isAgg ? agg : xin;
        const int kw = isAgg ? k0 : (k0 - 128);

#pragma unroll
        for (int it = 0; it < 4; ++it) {
            int idx = t + it * 256;
            int kr = idx >> 5, cq = idx & 31;
            float4 ww = *(const float4*)&W[(size_t)(kw + kr) * 128 + cq * 4];
            *(float4*)&Bs[kr][cq * 4] = ww;
        }
#pragma unroll
        for (int it = 0; it < 2; ++it) {
            int idx = t + it * 256;
            int r = idx >> 3, kq = idx & 7;
            int row_g = blockRow + r;
            float4 a = {0.f, 0.f, 0.f, 0.f};
            if (row_g < nrows)
                a = *(const float4*)&Asrc[(size_t)row_g * 128 + kw + kq * 4];
            *(float4*)&As[r][kq * 4] = a;
        }
        __syncthreads();

#pragma unroll
        for (int kk = 0; kk < 32; ++kk) {
            float aa[4];
            aa[0] = As[ty4 + 0][kk];
            aa[1] = As[ty4 + 1][kk];
            aa[2] = As[ty4 + 2][kk];
            aa[3] = As[ty4 + 3][kk];
            float4 b0 = *(const float4*)&Bs[kk][tx8];
            float4 b1 = *(const float4*)&Bs[kk][tx8 + 4];
            float bb[8] = {b0.x, b0.y, b0.z, b0.w, b1.x, b1.y, b1.z, b1.w};
#pragma unroll
            for (int j = 0; j < 4; ++j)
#pragma unroll
                for (int c = 0; c < 8; ++c)
                    acc[j][c] = fmaf(aa[j], bb[c], acc[j][c]);
        }
        __syncthreads();
    }

    float bv[8];
#pragma unroll
    for (int c = 0; c < 8; ++c) bv[c] = bias[tx8 + c];

    float s_loc[8], q_loc[8];
#pragma unroll
    for (int c = 0; c < 8; ++c) { s_loc[c] = 0.f; q_loc[c] = 0.f; }

#pragma unroll
    for (int j = 0; j < 4; ++j) {
        int row = blockRow + ty4 + j;
        if (row < nrows) {
            float o[8];
#pragma unroll
            for (int c = 0; c < 8; ++c) {
                o[c] = acc[j][c] + bv[c];
                s_loc[c] += o[c];
                q_loc[c] += o[c] * o[c];
            }
            float4 o0 = {o[0], o[1], o[2], o[3]};
            float4 o1 = {o[4], o[5], o[6], o[7]};
            *(float4*)&h[(size_t)row * 128 + tx8] = o0;
            *(float4*)&h[(size_t)row * 128 + tx8 + 4] = o1;
        }
    }

#pragma unroll
    for (int c = 0; c < 8; ++c) {
        s_loc[c] += __shfl_xor(s_loc[c], 16, 64);
        s_loc[c] += __shfl_xor(s_loc[c], 32, 64);
        q_loc[c] += __shfl_xor(q_loc[c], 16, 64);
        q_loc[c] += __shfl_xor(q_loc[c], 32, 64);
    }
    int wave = t >> 6;
    if ((t & 63) < 16) {
#pragma unroll
        for (int c = 0; c < 8; ++c) {
            redS[wave][tx8 + c] = s_loc[c];
            redQ[wave][tx8 + c] = q_loc[c];
        }
    }
    __syncthreads();
    if (t < 128) {
        float s = redS[0][t] + redS[1][t] + redS[2][t] + redS[3][t];
        float q = redQ[0][t] + redQ[1][t] + redQ[2][t] + redQ[3][t];
        atomicAdd(&stats[t], s);
        atomicAdd(&stats[128 + t], q);
    }
}

static void run_layer_atomic(const float* in_feat, const int* ei, int Nn, int Ee,
                             const float* Wl, const float* bl, const float* Wr,
                             const float* gamma, const float* beta,
                             float* agg, float* stats, float* out, hipStream_t stream) {
    long aggN = (long)Nn * 128;
    long n4 = aggN / 4;

    zero_stats_kernel<<<1, 256, 0, stream>>>(stats);
    int initBlocks = (int)((n4 + 255) / 256);
    if (initBlocks > 4096) initBlocks = 4096;
    init_sentinel_kernel<<<initBlocks, 256, 0, stream>>>((uint4*)agg, n4);
    int sb = (int)(((long)Ee * 32 + 255) / 256);
    scatter_max_kernel<<<sb, 256, 0, stream>>>((const float4*)in_feat, ei,
                                               (unsigned*)agg, Ee);
    int ub = (int)((aggN + 255) / 256);
    if (ub > 8192) ub = 8192;
    unmap_kernel<<<ub, 256, 0, stream>>>((unsigned*)agg, aggN);
    gemm_kernel<<<(Nn + 63) / 64, 256, 0, stream>>>(agg, in_feat, Wl, Wr, bl,
                                                    out, stats, Nn);
    int bnBlocks = (int)((n4 + 255) / 256);
    if (bnBlocks > 8192) bnBlocks = 8192;
    bn_relu_f32_kernel<<<bnBlocks, 256, 0, stream>>>((float4*)out, stats, gamma, beta,
                                                     1.0f / (float)Nn, n4);
}

// ============================================================================
// host-side orchestration
// ============================================================================
extern "C" void kernel_launch(void* const* d_in, const int* in_sizes, int n_in,
                              void* d_out, int out_size, void* d_ws, size_t ws_size,
                              hipStream_t stream) {
    (void)n_in; (void)out_size;
    const float* x     = (const float*)d_in[0];
    const int*   ei    = (const int*)d_in[1];
    const float* W0_l  = (const float*)d_in[2];
    const float* b0_l  = (const float*)d_in[3];
    const float* W0_r  = (const float*)d_in[4];
    const float* g0    = (const float*)d_in[5];
    const float* be0   = (const float*)d_in[6];
    const float* W1_l  = (const float*)d_in[7];
    const float* b1_l  = (const float*)d_in[8];
    const float* W1_r  = (const float*)d_in[9];
    const float* g1    = (const float*)d_in[10];
    const float* be1   = (const float*)d_in[11];

    int Nn = in_sizes[0] / 128;
    int Ee = in_sizes[1] / 2;
    long n4 = (long)Nn * 32;                   // float4 / uint2 row-elems
    float inv_n = 1.0f / (float)Nn;
    int NB = (Nn + 1023) / 1024;               // scan blocks

    char* p = (char*)d_ws;
    unsigned short* xy16 = (unsigned short*)p;  p += (size_t)Nn * 128 * 2;  // x16, later y16
    unsigned short* agg16 = (unsigned short*)p; p += (size_t)Nn * 128 * 2;
    float* stats0 = (float*)p;                  p += 256 * sizeof(float);
    float* stats1 = (float*)p;                  p += 256 * sizeof(float);
    unsigned short* Wt0 = (unsigned short*)p;   p += 128 * 256 * 2;
    unsigned short* Wt1 = (unsigned short*)p;   p += 128 * 256 * 2;
    int* head = (int*)p;                        p += (size_t)Nn * sizeof(int);
    int* deg = (int*)p;                         p += (size_t)Nn * sizeof(int);
    int* row_start = (int*)p;                   p += (size_t)(Nn + 1) * sizeof(int);
    int* bsum = (int*)p;                        p += (size_t)NB * sizeof(int);
    int* boff = (int*)p;                        p += (size_t)NB * sizeof(int);
    uint2* pair = (uint2*)p;                    p += (size_t)Ee * sizeof(uint2);
    int* ssrc = (int*)p;                        p += (size_t)Ee * sizeof(int);
    size_t needed = (size_t)(p - (char*)d_ws);
    float* out = (float*)d_out;
    unsigned short* h1 = (unsigned short*)d_out;   // h1-bf16 parked in d_out (dead by gemm2)

    if (ws_size >= needed && NB <= 1024) {
        // ---- bf16 MFMA path with CSR-flattened layer-2 gather ----
        int cvB = (int)((n4 + 255) / 256);
        if (cvB > 4096) cvB = 4096;
        int hB = (Nn + 255) / 256;
        prep_kernel<<<cvB + 256 + hB, 256, 0, stream>>>(
            (const float4*)x, (uint2*)xy16, n4, cvB,
            W0_l, W0_r, Wt0, W1_l, W1_r, Wt1, head, deg, Nn);
        link_hist_kernel<<<(Ee + 255) / 256, 256, 0, stream>>>(ei, head, pair, deg, Ee);
        block_sum_kernel<<<NB, 256, 0, stream>>>(deg, bsum, Nn);
        scan_bsums_kernel<<<1, 1024, 0, stream>>>(bsum, boff, NB);
        scan_apply_kernel<<<NB, 256, 0, stream>>>(deg, boff, row_start, Nn);

        int gB = (Nn * 16 + 255) / 256;
        int mB = (Nn + 127) / 128;
        int bnB = (int)((n4 + 255) / 256);
        if (bnB > 8192) bnB = 8192;

        // layer 1: agg1 <- max x16 (walk chains, emit CSR); h1(bf16) -> d_out
        gather_max_ll16_kernel<<<gB, 256, 0, stream>>>(
            (const uint4*)xy16, head, pair, row_start, ssrc,
            (uint4*)agg16, stats0, Nn);
        gemm_bf16_out16_kernel<<<mB, 256, 0, stream>>>(agg16, xy16, Wt0, b0_l,
                                                       h1, stats0, Nn);
        // layer 2: CSR gather; agg2 = relu(bn0(max h1)), y1 -> xy16
        gather_max_bn_csr_kernel<<<gB, 256, 0, stream>>>(
            (const uint4*)h1, row_start, ssrc, stats0, g0, be0, inv_n,
            (uint4*)agg16, (uint4*)xy16, stats1, Nn);
        gemm_bf16_out32_kernel<<<mB, 256, 0, stream>>>(agg16, xy16, Wt1, b1_l,
                                                       out, stats1, Nn);
        bn_relu_f32_kernel<<<bnB, 256, 0, stream>>>((float4*)out, stats1, g1, be1,
                                                    inv_n, n4);
    } else {
        // ---- fallback: fp32 atomic path ----
        float* agg = (float*)d_ws;
        float* fstats = (float*)((char*)d_ws + (size_t)Nn * 128 * sizeof(float));
        run_layer_atomic(x, ei, Nn, Ee, W0_l, b0_l, W0_r, g0, be0,
                         agg, fstats, out, stream);
        run_layer_atomic(out, ei, Nn, Ee, W1_l, b1_l, W1_r, g1, be1,
                         agg, fstats, out, stream);
    }
}

// Round 11
// 391.231 us; speedup vs baseline: 1.1846x; 1.1846x over previous
//
#include <hip/hip_runtime.h>
#include <stdint.h>

#define EPS_BN 1e-5f

typedef __attribute__((ext_vector_type(8))) short short8v;   // 8 bf16 = 4 VGPR
typedef __attribute__((ext_vector_type(4))) float f32x4;     // MFMA accumulator

__device__ __forceinline__ unsigned rne_bf16(float f) {      // round-to-nearest-even
    unsigned u = __float_as_uint(f);
    return (u + 0x7FFFu + ((u >> 16) & 1u)) >> 16;
}

// unpack/max/pack helpers for 8 bf16 held as uint4 (hi-garbage fmax trick:
// hi bf16 compared as raw u32-as-float — low-16 garbage is sub-ulp; ties
// truncate identically. lo bf16 via exact (u<<16).)
__device__ __forceinline__ void ld8v(float* a, uint4 v) {
    a[0] = __uint_as_float(v.x << 16); a[1] = __uint_as_float(v.x);
    a[2] = __uint_as_float(v.y << 16); a[3] = __uint_as_float(v.y);
    a[4] = __uint_as_float(v.z << 16); a[5] = __uint_as_float(v.z);
    a[6] = __uint_as_float(v.w << 16); a[7] = __uint_as_float(v.w);
}
__device__ __forceinline__ void fm8v(float* a, uint4 v) {
    a[0] = fmaxf(a[0], __uint_as_float(v.x << 16));
    a[1] = fmaxf(a[1], __uint_as_float(v.x));
    a[2] = fmaxf(a[2], __uint_as_float(v.y << 16));
    a[3] = fmaxf(a[3], __uint_as_float(v.y));
    a[4] = fmaxf(a[4], __uint_as_float(v.z << 16));
    a[5] = fmaxf(a[5], __uint_as_float(v.z));
    a[6] = fmaxf(a[6], __uint_as_float(v.w << 16));
    a[7] = fmaxf(a[7], __uint_as_float(v.w));
}
__device__ __forceinline__ uint4 pk8v(const float* a) {
    uint4 o;
    o.x = (__float_as_uint(a[0]) >> 16) | (__float_as_uint(a[1]) & 0xFFFF0000u);
    o.y = (__float_as_uint(a[2]) >> 16) | (__float_as_uint(a[3]) & 0xFFFF0000u);
    o.z = (__float_as_uint(a[4]) >> 16) | (__float_as_uint(a[5]) & 0xFFFF0000u);
    o.w = (__float_as_uint(a[6]) >> 16) | (__float_as_uint(a[7]) & 0xFFFF0000u);
    return o;
}

// ============================================================================
// merged prep: [0,cvB) x->bf16 | [cvB,cvB+256) wt0/wt1 | rest: head=-1
// ============================================================================
extern "C" __global__ __launch_bounds__(256)
void prep_kernel(const float4* __restrict__ x, uint2* __restrict__ x16, long n4, int cvB,
                 const float* __restrict__ Wl0, const float* __restrict__ Wr0,
                 unsigned short* __restrict__ Wt0,
                 const float* __restrict__ Wl1, const float* __restrict__ Wr1,
                 unsigned short* __restrict__ Wt1,
                 int* __restrict__ head, int Nn) {
    int b = blockIdx.x;
    if (b < cvB) {
        long i = (long)b * 256 + threadIdx.x;
        long stride = (long)cvB * 256;
        for (; i < n4; i += stride) {
            float4 v = x[i];
            uint2 o;
            o.x = rne_bf16(v.x) | (rne_bf16(v.y) << 16);
            o.y = rne_bf16(v.z) | (rne_bf16(v.w) << 16);
            x16[i] = o;
        }
    } else if (b < cvB + 256) {
        int wb = b - cvB;
        const float* Wl = (wb < 128) ? Wl0 : Wl1;
        const float* Wr = (wb < 128) ? Wr0 : Wr1;
        unsigned short* Wt = (wb < 128) ? Wt0 : Wt1;
        int idx = (wb & 127) * 256 + threadIdx.x;
        int col = idx >> 8, k = idx & 255;
        float v = (k < 128) ? Wl[(size_t)k * 128 + col]
                            : Wr[(size_t)(k - 128) * 128 + col];
        Wt[(size_t)col * 256 + k] = (unsigned short)rne_bf16(v);
    } else {
        int i = (b - cvB - 256) * 256 + threadIdx.x;
        if (i < Nn) head[i] = -1;
    }
}

// ============================================================================
// linked-list build: head[dst] -> latest edge, pair[e] = (src, prev same-dst)
// ============================================================================
extern "C" __global__ __launch_bounds__(256)
void link_kernel(const int* __restrict__ ei, int* __restrict__ head,
                 uint2* __restrict__ pair, int E) {
    int e = blockIdx.x * 256 + threadIdx.x;
    if (e < E) {
        int src = ei[e];
        int dst = ei[E + e];
        int old = atomicExch(&head[dst], e);
        uint2 p; p.x = (unsigned)src; p.y = (unsigned)old;
        pair[e] = p;                 // coalesced 8B write
    }
}

// ============================================================================
// gather-max (layer 1): 8 lanes/node, 2x uint4 (16 bf16 = 32B) per lane.
// 2x chains-in-flight per wave vs the 16-lane form (concurrency experiment).
// Also zeroes stats0[0..255] from block 0.
// ============================================================================
extern "C" __global__ __launch_bounds__(256, 8)
void gather_max_ll8_kernel(const uint4* __restrict__ x16r, const int* __restrict__ head,
                           const uint2* __restrict__ pair,
                           uint4* __restrict__ agg16, float* __restrict__ stats, int Nn) {
    if (blockIdx.x == 0 && threadIdx.x < 256) stats[threadIdx.x] = 0.0f;
    int t = blockIdx.x * 256 + threadIdx.x;
    int node = t >> 3;
    if (node >= Nn) return;
    int lane = t & 7;
    int e = head[node];
    uint4 o1, o2;
    if (e >= 0) {
        uint2 p = pair[e];
        const uint4* rp = x16r + (size_t)p.x * 16 + lane * 2;
        uint4 v1 = rp[0];
        uint4 v2 = rp[1];
        float a[16];
        ld8v(a, v1);
        ld8v(a + 8, v2);
        int en = (int)p.y;
        while (en >= 0) {
            uint2 pn = pair[en];                       // single dependent 8B load
            const uint4* q = x16r + (size_t)pn.x * 16 + lane * 2;
            uint4 w1 = q[0];
            uint4 w2 = q[1];
            en = (int)pn.y;
            fm8v(a, w1);
            fm8v(a + 8, w2);
        }
        o1 = pk8v(a);
        o2 = pk8v(a + 8);
    } else {
        o1.x = o1.y = o1.z = o1.w = 0u;   // PyG fills empty segments with 0
        o2 = o1;
    }
    uint4* op = agg16 + (size_t)node * 16 + lane * 2;
    op[0] = o1;
    op[1] = o2;
}

// ============================================================================
// gather-max + fused BN0 (layer 2), 16 lanes/node (proven r9 form):
//   agg2 = relu(bn0(max over neighbors of h1))   [monotone since gamma0 > 0]
//   y1   = relu(bn0(h1[node]))                   [lin_r input for gemm2]
// scale/shift staged transposed in LDS (stride-1, conflict-free).
// Also zeroes stats1[0..255] from block 0.
// ============================================================================
extern "C" __global__ __launch_bounds__(256, 8)
void gather_max_bn_kernel(const uint4* __restrict__ h1r, const int* __restrict__ head,
                          const uint2* __restrict__ pair,
                          const float* __restrict__ stats0,
                          const float* __restrict__ gamma, const float* __restrict__ beta,
                          float inv_n,
                          uint4* __restrict__ agg16, uint4* __restrict__ y16,
                          float* __restrict__ stats1, int Nn) {
    __shared__ float scT[8][17];   // [j][lane] : c = lane*8+j
    __shared__ float shT[8][17];
    {
        int t = threadIdx.x;
        if (t < 128) {
            float mu = stats0[t] * inv_n;
            float var = stats0[128 + t] * inv_n - mu * mu;
            float sc = gamma[t] * rsqrtf(var + EPS_BN);
            scT[t & 7][t >> 3] = sc;
            shT[t & 7][t >> 3] = beta[t] - mu * sc;
        }
        __syncthreads();
    }
    if (blockIdx.x == 0 && threadIdx.x < 256) stats1[threadIdx.x] = 0.0f;

    int t = blockIdx.x * 256 + threadIdx.x;
    int node = t >> 4;
    if (node >= Nn) return;
    int lane = t & 15;

    float sc[8], sh[8];
#pragma unroll
    for (int j = 0; j < 8; ++j) {
        sc[j] = scT[j][lane];      // stride-1 across the 16-lane group
        sh[j] = shT[j][lane];
    }

    // ---- own row -> y1 = relu(bn(h1[node])) ----
    {
        uint4 r = h1r[(size_t)node * 16 + lane];
        float v[8];
        ld8v(v, r);
        v[1] = __uint_as_float(__float_as_uint(v[1]) & 0xFFFF0000u);
        v[3] = __uint_as_float(__float_as_uint(v[3]) & 0xFFFF0000u);
        v[5] = __uint_as_float(__float_as_uint(v[5]) & 0xFFFF0000u);
        v[7] = __uint_as_float(__float_as_uint(v[7]) & 0xFFFF0000u);
        uint4 o;
        float w[8];
#pragma unroll
        for (int j = 0; j < 8; ++j) w[j] = fmaxf(fmaf(v[j], sc[j], sh[j]), 0.f);
        o.x = rne_bf16(w[0]) | (rne_bf16(w[1]) << 16);
        o.y = rne_bf16(w[2]) | (rne_bf16(w[3]) << 16);
        o.z = rne_bf16(w[4]) | (rne_bf16(w[5]) << 16);
        o.w = rne_bf16(w[6]) | (rne_bf16(w[7]) << 16);
        y16[(size_t)node * 16 + lane] = o;
    }

    // ---- neighbor max (raw), then relu(bn(.)) once ----
    int e = head[node];
    uint4 out;
    if (e >= 0) {
        uint2 p = pair[e];
        uint4 r = h1r[(size_t)p.x * 16 + lane];
        float a[8];
        ld8v(a, r);
        int en = (int)p.y;
        while (en >= 0) {
            uint2 pn = pair[en];
            uint4 v = h1r[(size_t)pn.x * 16 + lane];
            en = (int)pn.y;
            fm8v(a, v);
        }
        // clean hi-garbage before the affine map
        a[1] = __uint_as_float(__float_as_uint(a[1]) & 0xFFFF0000u);
        a[3] = __uint_as_float(__float_as_uint(a[3]) & 0xFFFF0000u);
        a[5] = __uint_as_float(__float_as_uint(a[5]) & 0xFFFF0000u);
        a[7] = __uint_as_float(__float_as_uint(a[7]) & 0xFFFF0000u);
        float w[8];
#pragma unroll
        for (int j = 0; j < 8; ++j) w[j] = fmaxf(fmaf(a[j], sc[j], sh[j]), 0.f);
        out.x = rne_bf16(w[0]) | (rne_bf16(w[1]) << 16);
        out.y = rne_bf16(w[2]) | (rne_bf16(w[3]) << 16);
        out.z = rne_bf16(w[4]) | (rne_bf16(w[5]) << 16);
        out.w = rne_bf16(w[6]) | (rne_bf16(w[7]) << 16);
    } else {
        out.x = out.y = out.z = out.w = 0u;   // PyG 0-fill (pre-GEMM, no BN)
    }
    agg16[(size_t)node * 16 + lane] = out;
}

// ============================================================================
// MFMA GEMM: acc = [agg16 | xin16] @ Wt^T + bias, fused BN col-stats.
// OUT_BF16=1 -> write h as bf16 (2B stores); else fp32.
// ============================================================================
template <int OUT_BF16>
__device__ __forceinline__
void gemm_bf16_body(const unsigned short* __restrict__ agg16,
                    const unsigned short* __restrict__ xin16,
                    const unsigned short* __restrict__ Wt,
                    const float* __restrict__ bias,
                    void* __restrict__ hout, float* __restrict__ stats, int nrows) {
    __shared__ float redS[4][128];
    __shared__ float redQ[4][128];

    const int t = threadIdx.x;
    const int w = t >> 6, l = t & 63;
    const int wm = w >> 1, wn = w & 1;
    const int r16 = l & 15, g = l >> 4;
    const int blockRow = blockIdx.x * 128;
    const int colBase = wn * 64;

    f32x4 acc[4][4];
#pragma unroll
    for (int m = 0; m < 4; ++m)
#pragma unroll
        for (int n = 0; n < 4; ++n) acc[m][n] = (f32x4){0.f, 0.f, 0.f, 0.f};

    const short8v az = {0, 0, 0, 0, 0, 0, 0, 0};

#pragma unroll
    for (int kt = 0; kt < 8; ++kt) {
        const unsigned short* Asrc = (kt < 4) ? agg16 : xin16;
        const int kofs = (kt < 4) ? kt * 32 : kt * 32 - 128;

        short8v b[4];
#pragma unroll
        for (int n = 0; n < 4; ++n) {
            int col = colBase + n * 16 + r16;
            b[n] = *(const short8v*)(Wt + (size_t)col * 256 + kt * 32 + g * 8);
        }
        short8v a[4];
#pragma unroll
        for (int m = 0; m < 4; ++m) {
            int row = blockRow + wm * 64 + m * 16 + r16;
            a[m] = (row < nrows)
                 ? *(const short8v*)(Asrc + (size_t)row * 128 + kofs + g * 8)
                 : az;
        }
#pragma unroll
        for (int m = 0; m < 4; ++m)
#pragma unroll
            for (int n = 0; n < 4; ++n)
                acc[m][n] = __builtin_amdgcn_mfma_f32_16x16x32_bf16(a[m], b[n], acc[m][n], 0, 0, 0);
    }

    // ---- epilogue: bias, store h, fused BN stats ----
    for (int i = t; i < 512; i += 256) {
        ((float*)redS)[i] = 0.f;
        ((float*)redQ)[i] = 0.f;
    }
    __syncthreads();

    float bcol[4];
#pragma unroll
    for (int n = 0; n < 4; ++n) bcol[n] = bias[colBase + n * 16 + r16];

    float s4[4] = {0.f, 0.f, 0.f, 0.f};
    float q4[4] = {0.f, 0.f, 0.f, 0.f};
#pragma unroll
    for (int m = 0; m < 4; ++m) {
#pragma unroll
        for (int reg = 0; reg < 4; ++reg) {
            int row = blockRow + wm * 64 + m * 16 + g * 4 + reg;   // C/D: row=(l>>4)*4+reg
            if (row < nrows) {
#pragma unroll
                for (int n = 0; n < 4; ++n) {
                    float o = acc[m][n][reg] + bcol[n];
                    int col = colBase + n * 16 + r16;               // col=l&15
                    if (OUT_BF16)
                        ((unsigned short*)hout)[(size_t)row * 128 + col] =
                            (unsigned short)rne_bf16(o);
                    else
                        ((float*)hout)[(size_t)row * 128 + col] = o;
                    s4[n] += o;
                    q4[n] += o * o;
                }
            }
        }
    }
#pragma unroll
    for (int n = 0; n < 4; ++n) {     // reduce over the 4 k-groups (same col)
        s4[n] += __shfl_xor(s4[n], 16, 64);
        s4[n] += __shfl_xor(s4[n], 32, 64);
        q4[n] += __shfl_xor(q4[n], 16, 64);
        q4[n] += __shfl_xor(q4[n], 32, 64);
    }
    if (g == 0) {
#pragma unroll
        for (int n = 0; n < 4; ++n) {
            redS[w][colBase + n * 16 + r16] = s4[n];
            redQ[w][colBase + n * 16 + r16] = q4[n];
        }
    }
    __syncthreads();
    if (t < 128) {
        float s = redS[0][t] + redS[1][t] + redS[2][t] + redS[3][t];
        float q = redQ[0][t] + redQ[1][t] + redQ[2][t] + redQ[3][t];
        atomicAdd(&stats[t], s);
        atomicAdd(&stats[128 + t], q);
    }
}

extern "C" __global__ __launch_bounds__(256)
void gemm_bf16_out16_kernel(const unsigned short* __restrict__ agg16,
                            const unsigned short* __restrict__ xin16,
                            const unsigned short* __restrict__ Wt,
                            const float* __restrict__ bias,
                            unsigned short* __restrict__ h, float* __restrict__ stats,
                            int nrows) {
    gemm_bf16_body<1>(agg16, xin16, Wt, bias, h, stats, nrows);
}

extern "C" __global__ __launch_bounds__(256)
void gemm_bf16_out32_kernel(const unsigned short* __restrict__ agg16,
                            const unsigned short* __restrict__ xin16,
                            const unsigned short* __restrict__ Wt,
                            const float* __restrict__ bias,
                            float* __restrict__ h, float* __restrict__ stats,
                            int nrows) {
    gemm_bf16_body<0>(agg16, xin16, Wt, bias, h, stats, nrows);
}

// ============================================================================
// final BN+ReLU in place fp32 (finalize fused per block)
// ============================================================================
extern "C" __global__ __launch_bounds__(256)
void bn_relu_f32_kernel(float4* __restrict__ h, const float* __restrict__ stats,
                        const float* __restrict__ gamma, const float* __restrict__ beta,
                        float inv_n, long n4) {
    __shared__ float s_ss[256];
    {
        int t = threadIdx.x;
        if (t < 128) {
            float mu = stats[t] * inv_n;
            float var = stats[128 + t] * inv_n - mu * mu;
            float sc = gamma[t] * rsqrtf(var + EPS_BN);
            s_ss[t] = sc;
            s_ss[128 + t] = beta[t] - mu * sc;
        }
        __syncthreads();
    }
    long i = (long)blockIdx.x * blockDim.x + threadIdx.x;
    long stride = (long)gridDim.x * blockDim.x;
    for (; i < n4; i += stride) {
        int c4 = (int)(i & 31) * 4;
        float4 v = h[i];
        v.x = fmaxf(fmaf(v.x, s_ss[c4 + 0], s_ss[128 + c4 + 0]), 0.f);
        v.y = fmaxf(fmaf(v.y, s_ss[c4 + 1], s_ss[128 + c4 + 1]), 0.f);
        v.z = fmaxf(fmaf(v.z, s_ss[c4 + 2], s_ss[128 + c4 + 2]), 0.f);
        v.w = fmaxf(fmaf(v.w, s_ss[c4 + 3], s_ss[128 + c4 + 3]), 0.f);
        h[i] = v;
    }
}

// ============================================================================
// fallback path (fp32 atomic scatter-max + VALU GEMM) — only if ws too small
// ============================================================================
__device__ __forceinline__ unsigned map_f(float f) {
    unsigned u = __float_as_uint(f);
    return (u & 0x80000000u) ? ~u : (u | 0x80000000u);
}
__device__ __forceinline__ float unmap_f(unsigned m) {
    return (m & 0x80000000u) ? __uint_as_float(m & 0x7FFFFFFFu) : __uint_as_float(~m);
}

extern "C" __global__ __launch_bounds__(256)
void init_sentinel_kernel(uint4* __restrict__ agg, long n4) {
    uint4 z = {0u, 0u, 0u, 0u};
    long i = (long)blockIdx.x * blockDim.x + threadIdx.x;
    long stride = (long)gridDim.x * blockDim.x;
    for (; i < n4; i += stride) agg[i] = z;
}

extern "C" __global__ __launch_bounds__(256)
void scatter_max_kernel(const float4* __restrict__ xin, const int* __restrict__ ei,
                        unsigned* __restrict__ agg, int E) {
    int t = blockIdx.x * 256 + threadIdx.x;
    int e = t >> 5;
    if (e >= E) return;
    int f4 = t & 31;
    int src = ei[e];
    int dst = ei[E + e];
    float4 v = xin[(size_t)src * 32 + f4];
    unsigned* p = agg + (size_t)dst * 128 + (size_t)f4 * 4;
    atomicMax(p + 0, map_f(v.x));
    atomicMax(p + 1, map_f(v.y));
    atomicMax(p + 2, map_f(v.z));
    atomicMax(p + 3, map_f(v.w));
}

extern "C" __global__ __launch_bounds__(256)
void unmap_kernel(unsigned* __restrict__ agg, long n) {
    long i = (long)blockIdx.x * blockDim.x + threadIdx.x;
    long stride = (long)gridDim.x * blockDim.x;
    for (; i < n; i += stride) {
        unsigned u = agg[i];
        agg[i] = __float_as_uint(u ? unmap_f(u) : 0.0f);
    }
}

extern "C" __global__
void zero_stats_kernel(float* __restrict__ stats) {
    stats[threadIdx.x] = 0.0f;
}

extern "C" __global__ __launch_bounds__(256)
void gemm_kernel(const float* __restrict__ agg, const float* __restrict__ xin,
                 const float* __restrict__ Wl, const float* __restrict__ Wr,
                 const float* __restrict__ bias, float* __restrict__ h,
                 float* __restrict__ stats, int nrows) {
    __shared__ __align__(16) float As[64][36];
    __shared__ __align__(16) float Bs[32][136];
    __shared__ float redS[4][128];
    __shared__ float redQ[4][128];

    const int t = threadIdx.x;
    const int tx = t & 15;
    const int ty = t >> 4;
    const int tx8 = tx * 8;
    const int ty4 = ty * 4;
    const int blockRow = blockIdx.x * 64;

    float acc[4][8];
#pragma unroll
    for (int j = 0; j < 4; ++j)
#pragma unroll
        for (int c = 0; c < 8; ++c) acc[j][c] = 0.0f;

    for (int kt = 0; kt < 8; ++kt) {
        const int k0 = kt * 32;
        const bool isAgg = (kt < 4);
        const float* W = isAgg ? Wl : Wr;
        const float* Asrc = isAgg ? agg : xin;
        const int kw = isAgg ? k0 : (k0 - 128);

#pragma unroll
        for (int it = 0; it < 4; ++it) {
            int idx = t + it * 256;
            int kr = idx >> 5, cq = idx & 31;
            float4 ww = *(const float4*)&W[(size_t)(kw + kr) * 128 + cq * 4];
            *(float4*)&Bs[kr][cq * 4] = ww;
        }
#pragma unroll
        for (int it = 0; it < 2; ++it) {
            int idx = t + it * 256;
            int r = idx >> 3, kq = idx & 7;
            int row_g = blockRow + r;
            float4 a = {0.f, 0.f, 0.f, 0.f};
            if (row_g < nrows)
                a = *(const float4*)&Asrc[(size_t)row_g * 128 + kw + kq * 4];
            *(float4*)&As[r][kq * 4] = a;
        }
        __syncthreads();

#pragma unroll
        for (int kk = 0; kk < 32; ++kk) {
            float aa[4];
            aa[0] = As[ty4 + 0][kk];
            aa[1] = As[ty4 + 1][kk];
            aa[2] = As[ty4 + 2][kk];
            aa[3] = As[ty4 + 3][kk];
            float4 b0 = *(const float4*)&Bs[kk][tx8];
            float4 b1 = *(const float4*)&Bs[kk][tx8 + 4];
            float bb[8] = {b0.x, b0.y, b0.z, b0.w, b1.x, b1.y, b1.z, b1.w};
#pragma unroll
            for (int j = 0; j < 4; ++j)
#pragma unroll
                for (int c = 0; c < 8; ++c)
                    acc[j][c] = fmaf(aa[j], bb[c], acc[j][c]);
        }
        __syncthreads();
    }

    float bv[8];
#pragma unroll
    for (int c = 0; c < 8; ++c) bv[c] = bias[tx8 + c];

    float s_loc[8], q_loc[8];
#pragma unroll
    for (int c = 0; c < 8; ++c) { s_loc[c] = 0.f; q_loc[c] = 0.f; }

#pragma unroll
    for (int j = 0; j < 4; ++j) {
        int row = blockRow + ty4 + j;
        if (row < nrows) {
            float o[8];
#pragma unroll
            for (int c = 0; c < 8; ++c) {
                o[c] = acc[j][c] + bv[c];
                s_loc[c] += o[c];
                q_loc[c] += o[c] * o[c];
            }
            float4 o0 = {o[0], o[1], o[2], o[3]};
            float4 o1 = {o[4], o[5], o[6], o[7]};
            *(float4*)&h[(size_t)row * 128 + tx8] = o0;
            *(float4*)&h[(size_t)row * 128 + tx8 + 4] = o1;
        }
    }

#pragma unroll
    for (int c = 0; c < 8; ++c) {
        s_loc[c] += __shfl_xor(s_loc[c], 16, 64);
        s_loc[c] += __shfl_xor(s_loc[c], 32, 64);
        q_loc[c] += __shfl_xor(q_loc[c], 16, 64);
        q_loc[c] += __shfl_xor(q_loc[c], 32, 64);
    }
    int wave = t >> 6;
    if ((t & 63) < 16) {
#pragma unroll
        for (int c = 0; c < 8; ++c) {
            redS[wave][tx8 + c] = s_loc[c];
            redQ[wave][tx8 + c] = q_loc[c];
        }
    }
    __syncthreads();
    if (t < 128) {
        float s = redS[0][t] + redS[1][t] + redS[2][t] + redS[3][t];
        float q = redQ[0][t] + redQ[1][t] + redQ[2][t] + redQ[3][t];
        atomicAdd(&stats[t], s);
        atomicAdd(&stats[128 + t], q);
    }
}

static void run_layer_atomic(const float* in_feat, const int* ei, int Nn, int Ee,
                             const float* Wl, const float* bl, const float* Wr,
                             const float* gamma, const float* beta,
                             float* agg, float* stats, float* out, hipStream_t stream) {
    long aggN = (long)Nn * 128;
    long n4 = aggN / 4;

    zero_stats_kernel<<<1, 256, 0, stream>>>(stats);
    int initBlocks = (int)((n4 + 255) / 256);
    if (initBlocks > 4096) initBlocks = 4096;
    init_sentinel_kernel<<<initBlocks, 256, 0, stream>>>((uint4*)agg, n4);
    int sb = (int)(((long)Ee * 32 + 255) / 256);
    scatter_max_kernel<<<sb, 256, 0, stream>>>((const float4*)in_feat, ei,
                                               (unsigned*)agg, Ee);
    int ub = (int)((aggN + 255) / 256);
    if (ub > 8192) ub = 8192;
    unmap_kernel<<<ub, 256, 0, stream>>>((unsigned*)agg, aggN);
    gemm_kernel<<<(Nn + 63) / 64, 256, 0, stream>>>(agg, in_feat, Wl, Wr, bl,
                                                    out, stats, Nn);
    int bnBlocks = (int)((n4 + 255) / 256);
    if (bnBlocks > 8192) bnBlocks = 8192;
    bn_relu_f32_kernel<<<bnBlocks, 256, 0, stream>>>((float4*)out, stats, gamma, beta,
                                                     1.0f / (float)Nn, n4);
}

// ============================================================================
// host-side orchestration
// ============================================================================
extern "C" void kernel_launch(void* const* d_in, const int* in_sizes, int n_in,
                              void* d_out, int out_size, void* d_ws, size_t ws_size,
                              hipStream_t stream) {
    (void)n_in; (void)out_size;
    const float* x     = (const float*)d_in[0];
    const int*   ei    = (const int*)d_in[1];
    const float* W0_l  = (const float*)d_in[2];
    const float* b0_l  = (const float*)d_in[3];
    const float* W0_r  = (const float*)d_in[4];
    const float* g0    = (const float*)d_in[5];
    const float* be0   = (const float*)d_in[6];
    const float* W1_l  = (const float*)d_in[7];
    const float* b1_l  = (const float*)d_in[8];
    const float* W1_r  = (const float*)d_in[9];
    const float* g1    = (const float*)d_in[10];
    const float* be1   = (const float*)d_in[11];

    int Nn = in_sizes[0] / 128;
    int Ee = in_sizes[1] / 2;
    long n4 = (long)Nn * 32;                   // float4 / uint2 row-elems
    float inv_n = 1.0f / (float)Nn;

    char* p = (char*)d_ws;
    unsigned short* xy16 = (unsigned short*)p;  p += (size_t)Nn * 128 * 2;  // x16, later y16
    unsigned short* agg16 = (unsigned short*)p; p += (size_t)Nn * 128 * 2;
    float* stats0 = (float*)p;                  p += 256 * sizeof(float);
    float* stats1 = (float*)p;                  p += 256 * sizeof(float);
    unsigned short* Wt0 = (unsigned short*)p;   p += 128 * 256 * 2;
    unsigned short* Wt1 = (unsigned short*)p;   p += 128 * 256 * 2;
    int* head = (int*)p;                        p += (size_t)Nn * sizeof(int);
    uint2* pair = (uint2*)p;                    p += (size_t)Ee * sizeof(uint2);
    size_t needed = (size_t)(p - (char*)d_ws);
    float* out = (float*)d_out;
    unsigned short* h1 = (unsigned short*)d_out;   // h1-bf16 parked in d_out (dead by gemm2)

    if (ws_size >= needed) {
        // ---- bf16 MFMA path ----
        int cvB = (int)((n4 + 255) / 256);
        if (cvB > 4096) cvB = 4096;
        int hB = (Nn + 255) / 256;
        prep_kernel<<<cvB + 256 + hB, 256, 0, stream>>>(
            (const float4*)x, (uint2*)xy16, n4, cvB,
            W0_l, W0_r, Wt0, W1_l, W1_r, Wt1, head, Nn);
        link_kernel<<<(Ee + 255) / 256, 256, 0, stream>>>(ei, head, pair, Ee);

        int g1B = (Nn * 8 + 255) / 256;
        int g2B = (Nn * 16 + 255) / 256;
        int mB = (Nn + 127) / 128;
        int bnB = (int)((n4 + 255) / 256);
        if (bnB > 8192) bnB = 8192;

        // layer 1: agg1 <- max x16 (8-lane experiment); h1(bf16) -> d_out
        gather_max_ll8_kernel<<<g1B, 256, 0, stream>>>(
            (const uint4*)xy16, head, pair, (uint4*)agg16, stats0, Nn);
        gemm_bf16_out16_kernel<<<mB, 256, 0, stream>>>(agg16, xy16, Wt0, b0_l,
                                                       h1, stats0, Nn);
        // layer 2: agg2 = relu(bn0(max h1)), y1 = relu(bn0(h1)) -> xy16
        gather_max_bn_kernel<<<g2B, 256, 0, stream>>>(
            (const uint4*)h1, head, pair, stats0, g0, be0, inv_n,
            (uint4*)agg16, (uint4*)xy16, stats1, Nn);
        gemm_bf16_out32_kernel<<<mB, 256, 0, stream>>>(agg16, xy16, Wt1, b1_l,
                                                       out, stats1, Nn);
        bn_relu_f32_kernel<<<bnB, 256, 0, stream>>>((float4*)out, stats1, g1, be1,
                                                    inv_n, n4);
    } else {
        // ---- fallback: fp32 atomic path ----
        float* agg = (float*)d_ws;
        float* fstats = (float*)((char*)d_ws + (size_t)Nn * 128 * sizeof(float));
        run_layer_atomic(x, ei, Nn, Ee, W0_l, b0_l, W0_r, g0, be0,
                         agg, fstats, out, stream);
        run_layer_atomic(out, ei, Nn, Ee, W1_l, b1_l, W1_r, g1, be1,
                         agg, fstats, out, stream);
    }
}